// Round 18
// baseline (134.314 us; speedup 1.0000x reference)
//
#include <hip/hip_runtime.h>
#include <math.h>

#define N_NODES 10000
#define N_EDGES 100000
#define HIDDEN  128
#define NHEAD   4
#define CHAN    128
#define IN_DIM  137      // 128 + 6 + 3
#define KPAD    160      // padded K for MFMA
#define NCOLS   1904     // 512*3 + 128 + 240
#define NPAD    1920     // padded to 15*128
#define LATD    6
#define DISD    3

#define PREP_BLOCKS 2500                       // 4 nodes/block
#define TRANS_TILES 26                         // 1664 cols / 64
#define WQE_BLOCKS  150                        // 240*160 / 256
#define WEBT_BLOCKS 128                        // 4*128*64 / 256

#define SCAT_BLOCKS ((N_EDGES + 255) / 256)    // 391
#define GEMM_BX 15
#define GEMM_BY ((N_NODES + 63) / 64)          // 157
#define NR16    628                            // ceil(10048/16) row groups (padded)
#define FRAG_STRIDE (5 * 64 * 8)               // ushorts per 16-group (2560)

typedef __attribute__((ext_vector_type(8))) short short8v;
typedef __attribute__((ext_vector_type(4))) float float4v;
typedef __attribute__((ext_vector_type(2))) float float2v;

__device__ inline unsigned short f2bf(float f) {
    unsigned u = __float_as_uint(f);
    unsigned r = 0x7fffu + ((u >> 16) & 1u);
    return (unsigned short)((u + r) >> 16);
}
__device__ inline float bf2f(unsigned short u) {
    return __uint_as_float(((unsigned)u) << 16);
}
// fragment-interleaved layout: frag[grp16][ks][lane][8], lane=(k%32/8)*16+lr
__device__ inline size_t frag_off(int grp16, int ks, int lane) {
    return (((size_t)grp16 * 5 + ks) * 64 + lane) * 8;
}
__device__ inline size_t frag_elem(int grp16, int lr, int k) {
    const int ks = k >> 5, g = (k >> 3) & 3, e = k & 7;
    return frag_off(grp16, ks, g * 16 + lr) + e;
}

// ---------------- Kernel 1: prep (LN + hist-zero) ∥ W-transpose ∥ wqe ∥ webt --
__global__ __launch_bounds__(256) void prep_weights_kernel(
    const float* __restrict__ nf, const float* __restrict__ frac,
    const float* __restrict__ lat, const int* __restrict__ n2g,
    const float* __restrict__ gamma, const float* __restrict__ beta,
    const float* __restrict__ Wq, const float* __restrict__ bq,
    const float* __restrict__ Wk, const float* __restrict__ bk,
    const float* __restrict__ Wv, const float* __restrict__ bv,
    const float* __restrict__ Wsk, const float* __restrict__ bsk,
    const float* __restrict__ We,
    unsigned short* __restrict__ xfrag, int* __restrict__ hist,
    unsigned short* __restrict__ wfrag, float* __restrict__ bias_all,
    unsigned short* __restrict__ webt)
{
    __shared__ __align__(16) unsigned short Tlds[64 * 168];
    const int tid = threadIdx.x;

    if (blockIdx.x < PREP_BLOCKS) {
        // ---- prep: LayerNorm + concat -> bf16 xfrag (fragment layout) ----
        int wave = tid >> 6;
        int lane = tid & 63;
        int n = blockIdx.x * 4 + wave;
        if (n >= N_NODES) return;

        float v0 = nf[n * HIDDEN + lane];
        float v1 = nf[n * HIDDEN + 64 + lane];
        float s  = v0 + v1;
        float sq = v0 * v0 + v1 * v1;
        #pragma unroll
        for (int m = 1; m < 64; m <<= 1) {
            s  += __shfl_xor(s, m);
            sq += __shfl_xor(sq, m);
        }
        float mean = s * (1.0f / 128.0f);
        float var  = sq * (1.0f / 128.0f) - mean * mean;   // biased variance
        float inv  = rsqrtf(var + 1e-5f);

        const int r16 = n >> 4, lr = n & 15;
        xfrag[frag_elem(r16, lr, lane)] =
            f2bf((v0 - mean) * inv * gamma[lane] + beta[lane]);
        xfrag[frag_elem(r16, lr, 64 + lane)] =
            f2bf((v1 - mean) * inv * gamma[64 + lane] + beta[64 + lane]);
        if (lane < LATD)
            xfrag[frag_elem(r16, lr, HIDDEN + lane)] = f2bf(lat[n2g[n] * LATD + lane]);
        if (lane < DISD)
            xfrag[frag_elem(r16, lr, HIDDEN + LATD + lane)] = f2bf(frac[n * DISD + lane]);
        if (lane >= 41)
            xfrag[frag_elem(r16, lr, 96 + lane)] = 0;       // k = 137..159 zero-pad
        if (lane == 0) hist[n] = 0;
    } else if (blockIdx.x < PREP_BLOCKS + TRANS_TILES) {
        // ---- LDS-tiled transpose -> wfrag (fragment layout), 64 cols/tile ----
        const int n0 = (blockIdx.x - PREP_BLOCKS) * 64;
        for (int i = tid; i < 160 * 64; i += 256) {
            const int k = i >> 6, n = i & 63;
            const int col = n0 + n;
            float val = 0.0f;
            if (k < IN_DIM) {
                if (col < 512)        val = Wq[(size_t)k * 512 + col];
                else if (col < 1024)  val = Wk[(size_t)k * 512 + (col - 512)];
                else if (col < 1536)  val = Wv[(size_t)k * 512 + (col - 1024)];
                else                  val = Wsk[(size_t)k * 128 + (col - 1536)];
            }
            Tlds[n * 168 + k] = f2bf(val);
        }
        __syncthreads();
        // write 4 col-groups x 5 ks x 64 lanes, 16B per task, fully coalesced
        for (int i = tid; i < 4 * 5 * 64; i += 256) {
            const int lane = i & 63;
            const int ks   = (i >> 6) % 5;
            const int c16l = i / (5 * 64);
            const int lr = lane & 15, g = lane >> 4;
            const int lcol = c16l * 16 + lr;
            const int k0 = ks * 32 + g * 8;
            const short8v v = *reinterpret_cast<const short8v*>(&Tlds[lcol * 168 + k0]);
            *reinterpret_cast<short8v*>(
                &wfrag[frag_off((n0 >> 4) + c16l, ks, lane)]) = v;
        }
        if (tid < 64) {
            const int col = n0 + tid;
            float b;
            if (col < 512)        b = bq[col];
            else if (col < 1024)  b = bk[col - 512];
            else if (col < 1536)  b = bv[col - 1024];
            else                  b = bsk[col - 1536];
            bias_all[col] = b;
        }
    } else if (blockIdx.x < PREP_BLOCKS + TRANS_TILES + WQE_BLOCKS) {
        // ---- wqe: fused Wqe = Wq (x) We^T per head -> wfrag cols 1664.. ----
        int idx = (blockIdx.x - PREP_BLOCKS - TRANS_TILES) * 256 + tid;
        if (idx >= 240 * KPAD) return;
        int hj = idx / KPAD, k = idx % KPAD;
        int h = hj / 60, j = hj % 60;
        float s = 0.0f;
        if (k < IN_DIM) {
            #pragma unroll 4
            for (int c = 0; c < 128; ++c)
                s += Wq[(size_t)k * 512 + h * 128 + c] * We[(size_t)j * 512 + h * 128 + c];
        }
        const int col = 1664 + hj;
        wfrag[frag_elem(col >> 4, col & 15, k)] = f2bf(s);
        if (k == KPAD - 1) {
            float b = 0.0f;
            #pragma unroll 4
            for (int c = 0; c < 128; ++c)
                b += bq[h * 128 + c] * We[(size_t)j * 512 + h * 128 + c];
            bias_all[col] = b;
        }
    } else {
        // ---- webt[h][c][j] bf16 for corrfin ----
        int g = (blockIdx.x - PREP_BLOCKS - TRANS_TILES - WQE_BLOCKS) * 256 + tid;
        if (g >= 4 * 128 * 64) return;
        int h = g >> 13, c = (g >> 6) & 127, j = g & 63;
        float v = (j < 60) ? We[(size_t)j * 512 + h * 128 + c] : 0.0f;
        webt[g] = f2bf(v);
    }
}

// ---------------- Kernel 2: histogram of dst --------------------------------
__global__ __launch_bounds__(256) void hist_kernel(
    const int* __restrict__ eidx, int* __restrict__ hist)
{
    int e = blockIdx.x * 256 + threadIdx.x;
    if (e < N_EDGES) atomicAdd(&hist[eidx[N_EDGES + e]], 1);
}

// ---------------- Kernel 3: exclusive scan (single block, plain loads) -------
__global__ __launch_bounds__(1024) void scan_kernel(
    const int* __restrict__ hist, int* __restrict__ offsets, int* __restrict__ cursor)
{
    __shared__ int part[1024];
    const int t = threadIdx.x;
    const int base = t * 10;
    int loc[10];
    int s = 0;
    #pragma unroll
    for (int i = 0; i < 10; ++i) {
        int v = (base + i < N_NODES) ? hist[base + i] : 0;
        loc[i] = s; s += v;
    }
    part[t] = s;
    __syncthreads();
    for (int off = 1; off < 1024; off <<= 1) {
        int v = (t >= off) ? part[t - off] : 0;
        __syncthreads();
        part[t] += v;
        __syncthreads();
    }
    int pre = (t > 0) ? part[t - 1] : 0;
    #pragma unroll
    for (int i = 0; i < 10; ++i)
        if (base + i < N_NODES) {
            offsets[base + i] = pre + loc[i];
            cursor[base + i]  = pre + loc[i];
        }
    if (t == 1023) offsets[N_NODES] = part[1023];
}

// ---------------- Kernel 4: scatter ∥ MFMA GEMM (no LDS, no barrier) ---------
// kvb layout per (node,h): 16 groups of 16B = {k[8ch] fp8 | v[8ch] fp8}
// so gather lane ql fetches k AND v for its 8 channels in ONE dwordx4.
__global__ __launch_bounds__(256, 4) void gemm_scatter_kernel(
    const unsigned short* __restrict__ xfrag, const unsigned short* __restrict__ wfrag,
    const float* __restrict__ bias_all,
    const int* __restrict__ eidx, const float* __restrict__ fdiff,
    int* __restrict__ cursor, int* __restrict__ sorted_src,
    float* __restrict__ sorted_fd,
    float* __restrict__ sq, unsigned short* __restrict__ qbuf,
    unsigned char* __restrict__ kvb)
{
    if (blockIdx.x < SCAT_BLOCKS) {
        int e = blockIdx.x * 256 + threadIdx.x;
        if (e >= N_EDGES) return;
        int src = eidx[e];
        int dst = eidx[N_EDGES + e];
        int pos = atomicAdd(&cursor[dst], 1);
        sorted_src[pos] = src;
        sorted_fd[pos * 3 + 0] = fdiff[e * 3 + 0];
        sorted_fd[pos * 3 + 1] = fdiff[e * 3 + 1];
        sorted_fd[pos * 3 + 2] = fdiff[e * 3 + 2];
        return;
    }

    const int bx   = blockIdx.x - SCAT_BLOCKS;
    const int row0 = (bx / GEMM_BX) * 64;
    const int col0 = (bx % GEMM_BX) * 128;
    const int tid  = threadIdx.x;
    const int l    = tid & 63;
    const int wid  = tid >> 6;
    const int wr   = (wid >> 1) * 32;
    const int wc   = (wid & 1) * 64;
    const int lr   = l & 15;
    const int r16  = (row0 + wr) >> 4;
    const int c16  = (col0 + wc) >> 4;

    // hoist A fragment loads (10 coalesced 1KB transactions, 40 VGPR)
    short8v a[2][5];
    #pragma unroll
    for (int ks = 0; ks < 5; ++ks)
        #pragma unroll
        for (int t = 0; t < 2; ++t)
            a[t][ks] = *reinterpret_cast<const short8v*>(
                &xfrag[frag_off(r16 + t, ks, l)]);

    float4v acc[2][4];
    #pragma unroll
    for (int tr = 0; tr < 2; ++tr)
        #pragma unroll
        for (int tc = 0; tc < 4; ++tc)
            acc[tr][tc] = (float4v){0.0f, 0.0f, 0.0f, 0.0f};

    #pragma unroll
    for (int ks = 0; ks < 5; ++ks) {
        short8v b[4];
        #pragma unroll
        for (int t = 0; t < 4; ++t)
            b[t] = *reinterpret_cast<const short8v*>(
                &wfrag[frag_off(c16 + t, ks, l)]);
        #pragma unroll
        for (int tr = 0; tr < 2; ++tr)
            #pragma unroll
            for (int tc = 0; tc < 4; ++tc)
                acc[tr][tc] = __builtin_amdgcn_mfma_f32_16x16x32_bf16(
                    a[tr][ks], b[tc], acc[tr][tc], 0, 0, 0);
    }

    #pragma unroll
    for (int tr = 0; tr < 2; ++tr) {
        #pragma unroll
        for (int tc = 0; tc < 4; ++tc) {
            const int col  = col0 + wc + tc * 16 + lr;
            const float bias = bias_all[col];
            #pragma unroll
            for (int j = 0; j < 4; ++j) {
                const int row = row0 + wr + tr * 16 + (l >> 4) * 4 + j;
                if (row < N_NODES) {
                    float val = acc[tr][tc][j] + bias;
                    if (col < 512) {                              // q -> bf16
                        qbuf[(size_t)row * 512 + col] = f2bf(val);
                    } else if (col < 1024) {                      // k -> fp8 interleaved
                        const int h = (col - 512) >> 7, ck = (col - 512) & 127;
                        int p = __builtin_amdgcn_cvt_pk_fp8_f32(val, val, 0, false);
                        kvb[((size_t)row * 4 + h) * 256 + (ck >> 3) * 16 + (ck & 7)]
                            = (unsigned char)(p & 0xFF);
                    } else if (col < 1536) {                      // v -> fp8 interleaved
                        const int h = (col - 1024) >> 7, cv = (col - 1024) & 127;
                        int p = __builtin_amdgcn_cvt_pk_fp8_f32(val, val, 0, false);
                        kvb[((size_t)row * 4 + h) * 256 + (cv >> 3) * 16 + 8 + (cv & 7)]
                            = (unsigned char)(p & 0xFF);
                    } else if (col < 1664) {                      // skip -> f32
                        sq[(size_t)row * 384 + (col - 1536)] = val;
                    } else if (col < NCOLS) {                     // qe -> f32
                        sq[(size_t)row * 384 + 128 + (col - 1664)] = val;
                    }
                }
            }
        }
    }
}

// ---------------- Kernel 5: per-node gather (quarter-wave per edge) ----------
// Block = 1 node, wave = head, QUARTER-wave (16 lanes x 8 ch) per edge,
// unroll 2 => 8 edges & 8 dwordx4 gathers in flight per wave per iteration.
// Lane ql owns channels 8ql..8ql+7 and emb slots j in {ql, ql+16, ql+32, ql+48}.
__global__ __launch_bounds__(256) void gather_kernel(
    const float* __restrict__ sq, const unsigned short* __restrict__ qbuf,
    const unsigned char* __restrict__ kvb,
    const int* __restrict__ offsets, const int* __restrict__ sorted_src,
    const float* __restrict__ sorted_fd,
    unsigned short* __restrict__ avbh, unsigned short* __restrict__ aggbuf,
    float* __restrict__ sumwbuf)
{
    const int n    = blockIdx.x;
    const int h    = threadIdx.x >> 6;
    const int l    = threadIdx.x & 63;
    const int ql   = l & 15;
    const int quarter = l >> 4;
    const float TWO_PI = 6.283185307179586f;
    const float scale  = 0.08838834764831845f;   // 1/sqrt(128)

    // q: 8 channels per lane (one dwordx4)
    const uint4 qu = *reinterpret_cast<const uint4*>(
        &qbuf[(size_t)n * 512 + h * 128 + 8 * ql]);
    float q8[8];
    q8[0] = bf2f((unsigned short)(qu.x & 0xffff)); q8[1] = bf2f((unsigned short)(qu.x >> 16));
    q8[2] = bf2f((unsigned short)(qu.y & 0xffff)); q8[3] = bf2f((unsigned short)(qu.y >> 16));
    q8[4] = bf2f((unsigned short)(qu.z & 0xffff)); q8[5] = bf2f((unsigned short)(qu.z >> 16));
    q8[6] = bf2f((unsigned short)(qu.w & 0xffff)); q8[7] = bf2f((unsigned short)(qu.w >> 16));

    // per-slot constants: slot t -> j = ql + 16t
    bool  sint[4]; int sdt[4]; float fct[4], qet[4];
    #pragma unroll
    for (int t = 0; t < 4; ++t) {
        const int j  = ql + 16 * t;
        const bool ok = (j < 60);
        const bool sn = (j < 30);
        const int jj = sn ? j : j - 30;
        int sd = jj / 10; if (sd > 2) sd = 2;        // clamp (j>=60 garbage slots)
        sint[t] = sn; sdt[t] = sd;
        fct[t]  = TWO_PI * (float)(jj % 10);
        qet[t]  = ok ? sq[(size_t)n * 384 + 128 + h * 60 + j] : 0.0f;
    }

    float av[8] = {0.f,0.f,0.f,0.f,0.f,0.f,0.f,0.f};
    float agg[4] = {0.f,0.f,0.f,0.f};
    float sumw = 0.f;
    const int e0 = offsets[n], e1 = offsets[n + 1];

    for (int base = e0; base < e1; base += 8) {
        const int eA = base + quarter;
        const int eB = base + quarter + 4;
        const bool okA = (eA < e1), okB = (eB < e1);
        const int iA = okA ? eA : e0;
        const int iB = okB ? eB : e0;
        const int srcA = sorted_src[iA];
        const int srcB = sorted_src[iB];
        float fdA[3], fdB[3];
        fdA[0] = sorted_fd[iA * 3];     fdB[0] = sorted_fd[iB * 3];
        fdA[1] = sorted_fd[iA * 3 + 1]; fdB[1] = sorted_fd[iB * 3 + 1];
        fdA[2] = sorted_fd[iA * 3 + 2]; fdB[2] = sorted_fd[iB * 3 + 2];
        const uint4 kvA = *reinterpret_cast<const uint4*>(
            kvb + ((size_t)srcA * 4 + h) * 256 + 16 * ql);
        const uint4 kvB = *reinterpret_cast<const uint4*>(
            kvb + ((size_t)srcB * 4 + h) * 256 + 16 * ql);

        float embA[4], embB[4];
        #pragma unroll
        for (int t = 0; t < 4; ++t) {
            const float vA = fdA[sdt[t]] * fct[t];
            const float vB = fdB[sdt[t]] * fct[t];
            embA[t] = sint[t] ? __sinf(vA) : __cosf(vA);
            embB[t] = sint[t] ? __sinf(vB) : __cosf(vB);
        }

        const float2v kA0 = __builtin_amdgcn_cvt_pk_f32_fp8(kvA.x, false);
        const float2v kA1 = __builtin_amdgcn_cvt_pk_f32_fp8(kvA.x, true);
        const float2v kA2 = __builtin_amdgcn_cvt_pk_f32_fp8(kvA.y, false);
        const float2v kA3 = __builtin_amdgcn_cvt_pk_f32_fp8(kvA.y, true);
        const float2v kB0 = __builtin_amdgcn_cvt_pk_f32_fp8(kvB.x, false);
        const float2v kB1 = __builtin_amdgcn_cvt_pk_f32_fp8(kvB.x, true);
        const float2v kB2 = __builtin_amdgcn_cvt_pk_f32_fp8(kvB.y, false);
        const float2v kB3 = __builtin_amdgcn_cvt_pk_f32_fp8(kvB.y, true);

        float pA = q8[0]*kA0[0] + q8[1]*kA0[1] + q8[2]*kA1[0] + q8[3]*kA1[1]
                 + q8[4]*kA2[0] + q8[5]*kA2[1] + q8[6]*kA3[0] + q8[7]*kA3[1]
                 + embA[0]*qet[0] + embA[1]*qet[1] + embA[2]*qet[2] + embA[3]*qet[3];
        float pB = q8[0]*kB0[0] + q8[1]*kB0[1] + q8[2]*kB1[0] + q8[3]*kB1[1]
                 + q8[4]*kB2[0] + q8[5]*kB2[1] + q8[6]*kB3[0] + q8[7]*kB3[1]
                 + embB[0]*qet[0] + embB[1]*qet[1] + embB[2]*qet[2] + embB[3]*qet[3];
        #pragma unroll
        for (int m = 1; m <= 8; m <<= 1) {
            pA += __shfl_xor(pA, m);
            pB += __shfl_xor(pB, m);
        }
        const float wA = okA ? __expf(pA * scale) : 0.0f;
        const float wB = okB ? __expf(pB * scale) : 0.0f;
        sumw += wA + wB;

        const float2v vA0 = __builtin_amdgcn_cvt_pk_f32_fp8(kvA.z, false);
        const float2v vA1 = __builtin_amdgcn_cvt_pk_f32_fp8(kvA.z, true);
        const float2v vA2 = __builtin_amdgcn_cvt_pk_f32_fp8(kvA.w, false);
        const float2v vA3 = __builtin_amdgcn_cvt_pk_f32_fp8(kvA.w, true);
        const float2v vB0 = __builtin_amdgcn_cvt_pk_f32_fp8(kvB.z, false);
        const float2v vB1 = __builtin_amdgcn_cvt_pk_f32_fp8(kvB.z, true);
        const float2v vB2 = __builtin_amdgcn_cvt_pk_f32_fp8(kvB.w, false);
        const float2v vB3 = __builtin_amdgcn_cvt_pk_f32_fp8(kvB.w, true);
        av[0] += wA*vA0[0] + wB*vB0[0];  av[1] += wA*vA0[1] + wB*vB0[1];
        av[2] += wA*vA1[0] + wB*vB1[0];  av[3] += wA*vA1[1] + wB*vB1[1];
        av[4] += wA*vA2[0] + wB*vB2[0];  av[5] += wA*vA2[1] + wB*vB2[1];
        av[6] += wA*vA3[0] + wB*vB3[0];  av[7] += wA*vA3[1] + wB*vB3[1];
        #pragma unroll
        for (int t = 0; t < 4; ++t)
            agg[t] += wA * embA[t] + wB * embB[t];
    }

    // combine the four quarters (xor 16, 32)
    #pragma unroll
    for (int m = 16; m <= 32; m <<= 1) {
        sumw += __shfl_xor(sumw, m);
        #pragma unroll
        for (int c = 0; c < 8; ++c) av[c] += __shfl_xor(av[c], m);
        #pragma unroll
        for (int t = 0; t < 4; ++t) agg[t] += __shfl_xor(agg[t], m);
    }

    if (quarter == 0) {
        uint4 st;
        st.x = (unsigned)f2bf(av[0]) | ((unsigned)f2bf(av[1]) << 16);
        st.y = (unsigned)f2bf(av[2]) | ((unsigned)f2bf(av[3]) << 16);
        st.z = (unsigned)f2bf(av[4]) | ((unsigned)f2bf(av[5]) << 16);
        st.w = (unsigned)f2bf(av[6]) | ((unsigned)f2bf(av[7]) << 16);
        *reinterpret_cast<uint4*>(&avbh[(size_t)n * 512 + h * 128 + 8 * ql]) = st;
        #pragma unroll
        for (int t = 0; t < 4; ++t)
            aggbuf[n * 256 + h * 64 + ql + 16 * t] = f2bf(agg[t]);  // j>=60: x0 by webt
        if (ql == 0) sumwbuf[n * 4 + h] = sumw;
    }
}

// ---------------- Kernel 6: corr MFMA + finalize (intra-lane cross-head) -----
__global__ __launch_bounds__(256) void corrfin_kernel(
    const unsigned short* __restrict__ webt, const unsigned short* __restrict__ aggbuf,
    const unsigned short* __restrict__ avbh, const float* __restrict__ sumwbuf,
    const float* __restrict__ sq, const float* __restrict__ nf,
    float* __restrict__ out)
{
    const int node0 = blockIdx.x * 64;
    const int tid = threadIdx.x;
    const int l   = tid & 63;
    const int w   = tid >> 6;
    const int lr  = l & 15;
    const int lk  = (l >> 4) * 8;
    const int nbase = node0 + w * 16;

    float4v acc[4][8];
    #pragma unroll
    for (int h = 0; h < 4; ++h)
        #pragma unroll
        for (int nn = 0; nn < 8; ++nn)
            acc[h][nn] = (float4v){0.0f, 0.0f, 0.0f, 0.0f};

    const int arow = (nbase + lr < N_NODES) ? (nbase + lr) : 0;  // clamp reads
    #pragma unroll
    for (int h = 0; h < 4; ++h) {
        #pragma unroll
        for (int ks = 0; ks < 2; ++ks) {
            const short8v a = *reinterpret_cast<const short8v*>(
                &aggbuf[(size_t)arow * 256 + h * 64 + ks * 32 + lk]);
            #pragma unroll
            for (int nn = 0; nn < 8; ++nn) {
                const short8v b = *reinterpret_cast<const short8v*>(
                    &webt[(size_t)(h * 128 + nn * 16 + lr) * 64 + ks * 32 + lk]);
                acc[h][nn] = __builtin_amdgcn_mfma_f32_16x16x32_bf16(a, b, acc[h][nn], 0, 0, 0);
            }
        }
    }

    // per-lane inverse sum-weights for its 4 output rows x 4 heads
    float inv_sw[4][4];
    #pragma unroll
    for (int j = 0; j < 4; ++j) {
        const int node = nbase + (l >> 4) * 4 + j;
        const int nrd  = (node < N_NODES) ? node : 0;
        #pragma unroll
        for (int h = 0; h < 4; ++h)
            inv_sw[j][h] = 1.0f / (sumwbuf[nrd * 4 + h] + 1e-16f);
    }

    #pragma unroll
    for (int nn = 0; nn < 8; ++nn) {
        const int col = nn * 16 + lr;
        #pragma unroll
        for (int j = 0; j < 4; ++j) {
            const int node = nbase + (l >> 4) * 4 + j;
            if (node < N_NODES) {
                float z = 0.0f;
                #pragma unroll
                for (int h = 0; h < 4; ++h)
                    z += (bf2f(avbh[(size_t)node * 512 + h * 128 + col]) + acc[h][nn][j])
                         * inv_sw[j][h];
                z = 0.25f * z + sq[(size_t)node * 384 + col];
                float si = z / (1.0f + __expf(-z));
                out[node * CHAN + col] = nf[node * CHAN + col] + si;
            }
        }
    }
}

// ---------------- launcher ---------------------------------------------------
extern "C" void kernel_launch(void* const* d_in, const int* in_sizes, int n_in,
                              void* d_out, int out_size, void* d_ws, size_t ws_size,
                              hipStream_t stream)
{
    const float* nf    = (const float*)d_in[0];
    const float* frac  = (const float*)d_in[1];
    const float* lat   = (const float*)d_in[2];
    const int*   eidx  = (const int*)  d_in[3];
    const int*   n2g   = (const int*)  d_in[4];
    const float* fdiff = (const float*)d_in[5];
    const float* gamma = (const float*)d_in[6];
    const float* beta  = (const float*)d_in[7];
    const float* Wq    = (const float*)d_in[8];
    const float* bq    = (const float*)d_in[9];
    const float* Wk    = (const float*)d_in[10];
    const float* bk    = (const float*)d_in[11];
    const float* Wv    = (const float*)d_in[12];
    const float* bv    = (const float*)d_in[13];
    const float* We    = (const float*)d_in[14];
    const float* Wsk   = (const float*)d_in[15];
    const float* bsk   = (const float*)d_in[16];
    float* out = (float*)d_out;

    // workspace layout
    float* sq        = (float*)d_ws;                               // N*384 (skip,qe)
    float* sumwbuf   = sq + (size_t)N_NODES * 384;                 // N*4
    float* bias_all  = sumwbuf + (size_t)N_NODES * 4;              // 1920
    float* sorted_fd = bias_all + NPAD;                            // E*3
    unsigned short* xfrag  = (unsigned short*)(sorted_fd + (size_t)N_EDGES * 3); // NR16*2560
    unsigned short* wfrag  = xfrag + (size_t)NR16 * FRAG_STRIDE;   // 120*2560
    unsigned short* webt   = wfrag + (size_t)(NPAD / 16) * FRAG_STRIDE; // 4*128*64
    unsigned short* aggbuf = webt + 4 * 128 * 64;                  // N*256
    unsigned short* qbuf   = aggbuf + (size_t)N_NODES * 256;       // N*512
    unsigned short* avbh   = qbuf + (size_t)N_NODES * 512;         // N*512 (bf16)
    unsigned char*  kvb    = (unsigned char*)(avbh + (size_t)N_NODES * 512); // N*4*256 bytes
    int* hist       = (int*)(kvb + (size_t)N_NODES * 4 * 256);     // N
    int* offsets    = hist + N_NODES;                              // N+1
    int* cursor     = offsets + N_NODES + 1;                       // N
    int* sorted_src = cursor + N_NODES;                            // E

    prep_weights_kernel<<<PREP_BLOCKS + TRANS_TILES + WQE_BLOCKS + WEBT_BLOCKS,
                          256, 0, stream>>>(
        nf, frac, lat, n2g, gamma, beta,
        Wq, bq, Wk, bk, Wv, bv, Wsk, bsk, We,
        xfrag, hist, wfrag, bias_all, webt);

    hist_kernel<<<(N_EDGES + 255) / 256, 256, 0, stream>>>(eidx, hist);
    scan_kernel<<<1, 1024, 0, stream>>>(hist, offsets, cursor);

    gemm_scatter_kernel<<<SCAT_BLOCKS + GEMM_BX * GEMM_BY, 256, 0, stream>>>(
        xfrag, wfrag, bias_all, eidx, fdiff, cursor, sorted_src, sorted_fd,
        sq, qbuf, kvb);

    gather_kernel<<<N_NODES, 256, 0, stream>>>(
        sq, qbuf, kvb, offsets, sorted_src, sorted_fd, avbh, aggbuf, sumwbuf);

    corrfin_kernel<<<(N_NODES + 63) / 64, 256, 0, stream>>>(
        webt, aggbuf, avbh, sumwbuf, sq, nf, out);
}

// Round 19
// 129.836 us; speedup vs baseline: 1.0345x; 1.0345x over previous
//
#include <hip/hip_runtime.h>
#include <math.h>

#define N_NODES 10000
#define N_EDGES 100000
#define HIDDEN  128
#define NHEAD   4
#define CHAN    128
#define IN_DIM  137      // 128 + 6 + 3
#define KPAD    160      // padded K for MFMA
#define NCOLS   1904     // 512*3 + 128 + 240
#define NPAD    1920     // padded to 15*128
#define LATD    6
#define DISD    3

#define PREP_BLOCKS 2500                       // 4 nodes/block
#define TRANS_TILES 26                         // 1664 cols / 64
#define WQE_BLOCKS  150                        // 240*160 / 256
#define WEBT_BLOCKS 128                        // 4*128*64 / 256

#define SCAT_BLOCKS ((N_EDGES + 255) / 256)    // 391
#define GEMM_BX 15
#define GEMM_BY ((N_NODES + 63) / 64)          // 157
#define NR16    628                            // ceil(10048/16) row groups (padded)
#define FRAG_STRIDE (5 * 64 * 8)               // ushorts per 16-group (2560)

typedef __attribute__((ext_vector_type(8))) short short8v;
typedef __attribute__((ext_vector_type(4))) float float4v;
typedef __attribute__((ext_vector_type(2))) float float2v;

__device__ inline unsigned short f2bf(float f) {
    unsigned u = __float_as_uint(f);
    unsigned r = 0x7fffu + ((u >> 16) & 1u);
    return (unsigned short)((u + r) >> 16);
}
__device__ inline float bf2f(unsigned short u) {
    return __uint_as_float(((unsigned)u) << 16);
}
// fragment-interleaved layout: frag[grp16][ks][lane][8], lane=(k%32/8)*16+lr
__device__ inline size_t frag_off(int grp16, int ks, int lane) {
    return (((size_t)grp16 * 5 + ks) * 64 + lane) * 8;
}
__device__ inline size_t frag_elem(int grp16, int lr, int k) {
    const int ks = k >> 5, g = (k >> 3) & 3, e = k & 7;
    return frag_off(grp16, ks, g * 16 + lr) + e;
}

// ---------------- Kernel 1: prep (LN + hist-zero) ∥ W-transpose ∥ wqe ∥ webt --
__global__ __launch_bounds__(256) void prep_weights_kernel(
    const float* __restrict__ nf, const float* __restrict__ frac,
    const float* __restrict__ lat, const int* __restrict__ n2g,
    const float* __restrict__ gamma, const float* __restrict__ beta,
    const float* __restrict__ Wq, const float* __restrict__ bq,
    const float* __restrict__ Wk, const float* __restrict__ bk,
    const float* __restrict__ Wv, const float* __restrict__ bv,
    const float* __restrict__ Wsk, const float* __restrict__ bsk,
    const float* __restrict__ We,
    unsigned short* __restrict__ xfrag, int* __restrict__ hist,
    unsigned short* __restrict__ wfrag, float* __restrict__ bias_all,
    unsigned short* __restrict__ webt)
{
    __shared__ __align__(16) unsigned short Tlds[64 * 168];
    const int tid = threadIdx.x;

    if (blockIdx.x < PREP_BLOCKS) {
        // ---- prep: LayerNorm + concat -> bf16 xfrag (fragment layout) ----
        int wave = tid >> 6;
        int lane = tid & 63;
        int n = blockIdx.x * 4 + wave;
        if (n >= N_NODES) return;

        float v0 = nf[n * HIDDEN + lane];
        float v1 = nf[n * HIDDEN + 64 + lane];
        float s  = v0 + v1;
        float sq = v0 * v0 + v1 * v1;
        #pragma unroll
        for (int m = 1; m < 64; m <<= 1) {
            s  += __shfl_xor(s, m);
            sq += __shfl_xor(sq, m);
        }
        float mean = s * (1.0f / 128.0f);
        float var  = sq * (1.0f / 128.0f) - mean * mean;   // biased variance
        float inv  = rsqrtf(var + 1e-5f);

        const int r16 = n >> 4, lr = n & 15;
        xfrag[frag_elem(r16, lr, lane)] =
            f2bf((v0 - mean) * inv * gamma[lane] + beta[lane]);
        xfrag[frag_elem(r16, lr, 64 + lane)] =
            f2bf((v1 - mean) * inv * gamma[64 + lane] + beta[64 + lane]);
        if (lane < LATD)
            xfrag[frag_elem(r16, lr, HIDDEN + lane)] = f2bf(lat[n2g[n] * LATD + lane]);
        if (lane < DISD)
            xfrag[frag_elem(r16, lr, HIDDEN + LATD + lane)] = f2bf(frac[n * DISD + lane]);
        if (lane >= 41)
            xfrag[frag_elem(r16, lr, 96 + lane)] = 0;       // k = 137..159 zero-pad
        if (lane == 0) hist[n] = 0;
    } else if (blockIdx.x < PREP_BLOCKS + TRANS_TILES) {
        // ---- LDS-tiled transpose -> wfrag (fragment layout), 64 cols/tile ----
        const int n0 = (blockIdx.x - PREP_BLOCKS) * 64;
        for (int i = tid; i < 160 * 64; i += 256) {
            const int k = i >> 6, n = i & 63;
            const int col = n0 + n;
            float val = 0.0f;
            if (k < IN_DIM) {
                if (col < 512)        val = Wq[(size_t)k * 512 + col];
                else if (col < 1024)  val = Wk[(size_t)k * 512 + (col - 512)];
                else if (col < 1536)  val = Wv[(size_t)k * 512 + (col - 1024)];
                else                  val = Wsk[(size_t)k * 128 + (col - 1536)];
            }
            Tlds[n * 168 + k] = f2bf(val);
        }
        __syncthreads();
        // write 4 col-groups x 5 ks x 64 lanes, 16B per task, fully coalesced
        for (int i = tid; i < 4 * 5 * 64; i += 256) {
            const int lane = i & 63;
            const int ks   = (i >> 6) % 5;
            const int c16l = i / (5 * 64);
            const int lr = lane & 15, g = lane >> 4;
            const int lcol = c16l * 16 + lr;
            const int k0 = ks * 32 + g * 8;
            const short8v v = *reinterpret_cast<const short8v*>(&Tlds[lcol * 168 + k0]);
            *reinterpret_cast<short8v*>(
                &wfrag[frag_off((n0 >> 4) + c16l, ks, lane)]) = v;
        }
        if (tid < 64) {
            const int col = n0 + tid;
            float b;
            if (col < 512)        b = bq[col];
            else if (col < 1024)  b = bk[col - 512];
            else if (col < 1536)  b = bv[col - 1024];
            else                  b = bsk[col - 1536];
            bias_all[col] = b;
        }
    } else if (blockIdx.x < PREP_BLOCKS + TRANS_TILES + WQE_BLOCKS) {
        // ---- wqe: fused Wqe = Wq (x) We^T per head -> wfrag cols 1664.. ----
        int idx = (blockIdx.x - PREP_BLOCKS - TRANS_TILES) * 256 + tid;
        if (idx >= 240 * KPAD) return;
        int hj = idx / KPAD, k = idx % KPAD;
        int h = hj / 60, j = hj % 60;
        float s = 0.0f;
        if (k < IN_DIM) {
            #pragma unroll 4
            for (int c = 0; c < 128; ++c)
                s += Wq[(size_t)k * 512 + h * 128 + c] * We[(size_t)j * 512 + h * 128 + c];
        }
        const int col = 1664 + hj;
        wfrag[frag_elem(col >> 4, col & 15, k)] = f2bf(s);
        if (k == KPAD - 1) {
            float b = 0.0f;
            #pragma unroll 4
            for (int c = 0; c < 128; ++c)
                b += bq[h * 128 + c] * We[(size_t)j * 512 + h * 128 + c];
            bias_all[col] = b;
        }
    } else {
        // ---- webt[h][c][j] bf16 for corrfin ----
        int g = (blockIdx.x - PREP_BLOCKS - TRANS_TILES - WQE_BLOCKS) * 256 + tid;
        if (g >= 4 * 128 * 64) return;
        int h = g >> 13, c = (g >> 6) & 127, j = g & 63;
        float v = (j < 60) ? We[(size_t)j * 512 + h * 128 + c] : 0.0f;
        webt[g] = f2bf(v);
    }
}

// ---------------- Kernel 2: histogram of dst --------------------------------
__global__ __launch_bounds__(256) void hist_kernel(
    const int* __restrict__ eidx, int* __restrict__ hist)
{
    int e = blockIdx.x * 256 + threadIdx.x;
    if (e < N_EDGES) atomicAdd(&hist[eidx[N_EDGES + e]], 1);
}

// ---------------- Kernel 3: exclusive scan (single block, plain loads) -------
__global__ __launch_bounds__(1024) void scan_kernel(
    const int* __restrict__ hist, int* __restrict__ offsets, int* __restrict__ cursor)
{
    __shared__ int part[1024];
    const int t = threadIdx.x;
    const int base = t * 10;
    int loc[10];
    int s = 0;
    #pragma unroll
    for (int i = 0; i < 10; ++i) {
        int v = (base + i < N_NODES) ? hist[base + i] : 0;
        loc[i] = s; s += v;
    }
    part[t] = s;
    __syncthreads();
    for (int off = 1; off < 1024; off <<= 1) {
        int v = (t >= off) ? part[t - off] : 0;
        __syncthreads();
        part[t] += v;
        __syncthreads();
    }
    int pre = (t > 0) ? part[t - 1] : 0;
    #pragma unroll
    for (int i = 0; i < 10; ++i)
        if (base + i < N_NODES) {
            offsets[base + i] = pre + loc[i];
            cursor[base + i]  = pre + loc[i];
        }
    if (t == 1023) offsets[N_NODES] = part[1023];
}

// ---------------- Kernel 4: scatter ∥ MFMA GEMM (no LDS, no barrier) ---------
// A fragments hoisted (10 coalesced 1KB loads); B loaded per-ks inside the
// unrolled loop so the compiler pipelines loads under MFMAs. launch_bounds
// (256,4) caps VGPR at 128 -> 4+ waves/SIMD.
__global__ __launch_bounds__(256, 4) void gemm_scatter_kernel(
    const unsigned short* __restrict__ xfrag, const unsigned short* __restrict__ wfrag,
    const float* __restrict__ bias_all,
    const int* __restrict__ eidx, const float* __restrict__ fdiff,
    int* __restrict__ cursor, int* __restrict__ sorted_src,
    float* __restrict__ sorted_fd,
    float* __restrict__ sq, unsigned short* __restrict__ qbuf,
    unsigned char* __restrict__ kvb)
{
    if (blockIdx.x < SCAT_BLOCKS) {
        int e = blockIdx.x * 256 + threadIdx.x;
        if (e >= N_EDGES) return;
        int src = eidx[e];
        int dst = eidx[N_EDGES + e];
        int pos = atomicAdd(&cursor[dst], 1);
        sorted_src[pos] = src;
        sorted_fd[pos * 3 + 0] = fdiff[e * 3 + 0];
        sorted_fd[pos * 3 + 1] = fdiff[e * 3 + 1];
        sorted_fd[pos * 3 + 2] = fdiff[e * 3 + 2];
        return;
    }

    const int bx   = blockIdx.x - SCAT_BLOCKS;
    const int row0 = (bx / GEMM_BX) * 64;
    const int col0 = (bx % GEMM_BX) * 128;
    const int tid  = threadIdx.x;
    const int l    = tid & 63;
    const int wid  = tid >> 6;
    const int wr   = (wid >> 1) * 32;
    const int wc   = (wid & 1) * 64;
    const int lr   = l & 15;
    const int r16  = (row0 + wr) >> 4;
    const int c16  = (col0 + wc) >> 4;

    // hoist A fragment loads (10 coalesced 1KB transactions, 40 VGPR)
    short8v a[2][5];
    #pragma unroll
    for (int ks = 0; ks < 5; ++ks)
        #pragma unroll
        for (int t = 0; t < 2; ++t)
            a[t][ks] = *reinterpret_cast<const short8v*>(
                &xfrag[frag_off(r16 + t, ks, l)]);

    float4v acc[2][4];
    #pragma unroll
    for (int tr = 0; tr < 2; ++tr)
        #pragma unroll
        for (int tc = 0; tc < 4; ++tc)
            acc[tr][tc] = (float4v){0.0f, 0.0f, 0.0f, 0.0f};

    #pragma unroll
    for (int ks = 0; ks < 5; ++ks) {
        short8v b[4];
        #pragma unroll
        for (int t = 0; t < 4; ++t)
            b[t] = *reinterpret_cast<const short8v*>(
                &wfrag[frag_off(c16 + t, ks, l)]);
        #pragma unroll
        for (int tr = 0; tr < 2; ++tr)
            #pragma unroll
            for (int tc = 0; tc < 4; ++tc)
                acc[tr][tc] = __builtin_amdgcn_mfma_f32_16x16x32_bf16(
                    a[tr][ks], b[tc], acc[tr][tc], 0, 0, 0);
    }

    #pragma unroll
    for (int tr = 0; tr < 2; ++tr) {
        #pragma unroll
        for (int tc = 0; tc < 4; ++tc) {
            const int col  = col0 + wc + tc * 16 + lr;
            const float bias = bias_all[col];
            #pragma unroll
            for (int j = 0; j < 4; ++j) {
                const int row = row0 + wr + tr * 16 + (l >> 4) * 4 + j;
                if (row < N_NODES) {
                    float val = acc[tr][tc][j] + bias;
                    if (col < 512) {                              // q -> bf16
                        qbuf[(size_t)row * 512 + col] = f2bf(val);
                    } else if (col < 1024) {                      // k -> fp8 e4m3
                        const int h = (col - 512) >> 7, ck = (col - 512) & 127;
                        int p = __builtin_amdgcn_cvt_pk_fp8_f32(val, val, 0, false);
                        kvb[((size_t)row * 4 + h) * 256 + ck] = (unsigned char)(p & 0xFF);
                    } else if (col < 1536) {                      // v -> fp8 e4m3
                        const int h = (col - 1024) >> 7, cv = (col - 1024) & 127;
                        int p = __builtin_amdgcn_cvt_pk_fp8_f32(val, val, 0, false);
                        kvb[((size_t)row * 4 + h) * 256 + 128 + cv] = (unsigned char)(p & 0xFF);
                    } else if (col < 1664) {                      // skip -> f32
                        sq[(size_t)row * 384 + (col - 1536)] = val;
                    } else if (col < NCOLS) {                     // qe -> f32
                        sq[(size_t)row * 384 + 128 + (col - 1664)] = val;
                    }
                }
            }
        }
    }
}

// ---------------- Kernel 5: per-node gather ----------------------------------
// Block = 1 node, wave = head, half-wave per edge, unroll 2.
// Per (src,h): one contiguous 256B region (k fp8 128B || v fp8 128B).
// av stored bf16 (accumulated f32 in registers).
__global__ __launch_bounds__(256) void gather_kernel(
    const float* __restrict__ sq, const unsigned short* __restrict__ qbuf,
    const unsigned char* __restrict__ kvb,
    const int* __restrict__ offsets, const int* __restrict__ sorted_src,
    const float* __restrict__ sorted_fd,
    unsigned short* __restrict__ avbh, unsigned short* __restrict__ aggbuf,
    float* __restrict__ sumwbuf)
{
    const int n    = blockIdx.x;
    const int h    = threadIdx.x >> 6;
    const int l    = threadIdx.x & 63;
    const int hl   = l & 31;
    const int half = l >> 5;
    const float TWO_PI = 6.283185307179586f;
    const float scale  = 0.08838834764831845f;   // 1/sqrt(128)

    const ushort4 qv = *reinterpret_cast<const ushort4*>(
        &qbuf[(size_t)n * 512 + h * 128 + 4 * hl]);
    const float q4x = bf2f(qv.x), q4y = bf2f(qv.y);
    const float q4z = bf2f(qv.z), q4w = bf2f(qv.w);
    const float qe_a = sq[(size_t)n * 384 + 128 + h * 60 + hl];  // j1 = hl (<60)
    const bool  v2ok = (hl < 28);                                // j2 = hl+32 < 60
    const float qe_b = v2ok ? sq[(size_t)n * 384 + 128 + h * 60 + hl + 32] : 0.0f;

    // emb slot 1: j1 = hl; slot 2: j2 = hl+32 (always cos)
    const int   jj1  = (hl < 30) ? hl : hl - 30;
    const int   sd1  = jj1 / 10;
    const float fc1  = TWO_PI * (float)(jj1 % 10);
    const bool  sin1 = (hl < 30);
    const int   jj2  = hl + 2;
    const int   sd2  = v2ok ? (jj2 / 10) : 0;
    const float fc2  = v2ok ? TWO_PI * (float)(jj2 % 10) : 0.0f;

    float ax = 0.f, ay = 0.f, az = 0.f, aw = 0.f;
    float agg1 = 0.f, agg2 = 0.f, sumw = 0.f;
    const int e0 = offsets[n], e1 = offsets[n + 1];

    for (int base = e0; base < e1; base += 4) {
        const int eA = base + half;
        const int eB = base + half + 2;
        const bool okA = (eA < e1), okB = (eB < e1);
        const int iA = okA ? eA : e0;
        const int iB = okB ? eB : e0;
        const int srcA = sorted_src[iA];
        const int srcB = sorted_src[iB];
        const float fdA1 = sorted_fd[iA * 3 + sd1];
        const float fdA2 = sorted_fd[iA * 3 + sd2];
        const float fdB1 = sorted_fd[iB * 3 + sd1];
        const float fdB2 = sorted_fd[iB * 3 + sd2];
        const unsigned char* pA = kvb + ((size_t)srcA * 4 + h) * 256;
        const unsigned char* pB = kvb + ((size_t)srcB * 4 + h) * 256;
        const unsigned kAu = *reinterpret_cast<const unsigned*>(pA + 4 * hl);
        const unsigned vAu = *reinterpret_cast<const unsigned*>(pA + 128 + 4 * hl);
        const unsigned kBu = *reinterpret_cast<const unsigned*>(pB + 4 * hl);
        const unsigned vBu = *reinterpret_cast<const unsigned*>(pB + 128 + 4 * hl);

        const float eA1 = sin1 ? __sinf(fdA1 * fc1) : __cosf(fdA1 * fc1);
        const float eA2 = __cosf(fdA2 * fc2);
        const float eB1 = sin1 ? __sinf(fdB1 * fc1) : __cosf(fdB1 * fc1);
        const float eB2 = __cosf(fdB2 * fc2);

        const float2v kA01 = __builtin_amdgcn_cvt_pk_f32_fp8(kAu, false);
        const float2v kA23 = __builtin_amdgcn_cvt_pk_f32_fp8(kAu, true);
        const float2v kB01 = __builtin_amdgcn_cvt_pk_f32_fp8(kBu, false);
        const float2v kB23 = __builtin_amdgcn_cvt_pk_f32_fp8(kBu, true);

        float pAs = q4x * kA01[0] + q4y * kA01[1]
                  + q4z * kA23[0] + q4w * kA23[1]
                  + eA1 * qe_a + eA2 * qe_b;
        float pBs = q4x * kB01[0] + q4y * kB01[1]
                  + q4z * kB23[0] + q4w * kB23[1]
                  + eB1 * qe_a + eB2 * qe_b;
        #pragma unroll
        for (int m = 1; m <= 16; m <<= 1) {
            pAs += __shfl_xor(pAs, m);
            pBs += __shfl_xor(pBs, m);
        }
        const float wA = okA ? __expf(pAs * scale) : 0.0f;
        const float wB = okB ? __expf(pBs * scale) : 0.0f;
        sumw += wA + wB;

        const float2v vA01 = __builtin_amdgcn_cvt_pk_f32_fp8(vAu, false);
        const float2v vA23 = __builtin_amdgcn_cvt_pk_f32_fp8(vAu, true);
        const float2v vB01 = __builtin_amdgcn_cvt_pk_f32_fp8(vBu, false);
        const float2v vB23 = __builtin_amdgcn_cvt_pk_f32_fp8(vBu, true);
        ax += wA * vA01[0] + wB * vB01[0];
        ay += wA * vA01[1] + wB * vB01[1];
        az += wA * vA23[0] + wB * vB23[0];
        aw += wA * vA23[1] + wB * vB23[1];
        agg1 += wA * eA1 + wB * eB1;
        if (v2ok) agg2 += wA * eA2 + wB * eB2;
    }

    // combine the two halves
    sumw += __shfl_xor(sumw, 32);
    ax += __shfl_xor(ax, 32);  ay += __shfl_xor(ay, 32);
    az += __shfl_xor(az, 32);  aw += __shfl_xor(aw, 32);
    agg1 += __shfl_xor(agg1, 32);
    agg2 += __shfl_xor(agg2, 32);

    if (half == 0) {
        ushort4 r;
        r.x = f2bf(ax); r.y = f2bf(ay); r.z = f2bf(az); r.w = f2bf(aw);
        *reinterpret_cast<ushort4*>(&avbh[(size_t)n * 512 + h * 128 + 4 * hl]) = r;
        aggbuf[n * 256 + h * 64 + hl]      = f2bf(agg1);           // j = hl
        aggbuf[n * 256 + h * 64 + 32 + hl] = f2bf(agg2);           // j = hl+32
        if (hl == 0) sumwbuf[n * 4 + h] = sumw;
    }
}

// ---------------- Kernel 6: corr MFMA + finalize (intra-lane cross-head) -----
__global__ __launch_bounds__(256) void corrfin_kernel(
    const unsigned short* __restrict__ webt, const unsigned short* __restrict__ aggbuf,
    const unsigned short* __restrict__ avbh, const float* __restrict__ sumwbuf,
    const float* __restrict__ sq, const float* __restrict__ nf,
    float* __restrict__ out)
{
    const int node0 = blockIdx.x * 64;
    const int tid = threadIdx.x;
    const int l   = tid & 63;
    const int w   = tid >> 6;
    const int lr  = l & 15;
    const int lk  = (l >> 4) * 8;
    const int nbase = node0 + w * 16;

    float4v acc[4][8];
    #pragma unroll
    for (int h = 0; h < 4; ++h)
        #pragma unroll
        for (int nn = 0; nn < 8; ++nn)
            acc[h][nn] = (float4v){0.0f, 0.0f, 0.0f, 0.0f};

    const int arow = (nbase + lr < N_NODES) ? (nbase + lr) : 0;  // clamp reads
    #pragma unroll
    for (int h = 0; h < 4; ++h) {
        #pragma unroll
        for (int ks = 0; ks < 2; ++ks) {
            const short8v a = *reinterpret_cast<const short8v*>(
                &aggbuf[(size_t)arow * 256 + h * 64 + ks * 32 + lk]);
            #pragma unroll
            for (int nn = 0; nn < 8; ++nn) {
                const short8v b = *reinterpret_cast<const short8v*>(
                    &webt[(size_t)(h * 128 + nn * 16 + lr) * 64 + ks * 32 + lk]);
                acc[h][nn] = __builtin_amdgcn_mfma_f32_16x16x32_bf16(a, b, acc[h][nn], 0, 0, 0);
            }
        }
    }

    // per-lane inverse sum-weights for its 4 output rows x 4 heads
    float inv_sw[4][4];
    #pragma unroll
    for (int j = 0; j < 4; ++j) {
        const int node = nbase + (l >> 4) * 4 + j;
        const int nrd  = (node < N_NODES) ? node : 0;
        #pragma unroll
        for (int h = 0; h < 4; ++h)
            inv_sw[j][h] = 1.0f / (sumwbuf[nrd * 4 + h] + 1e-16f);
    }

    #pragma unroll
    for (int nn = 0; nn < 8; ++nn) {
        const int col = nn * 16 + lr;
        #pragma unroll
        for (int j = 0; j < 4; ++j) {
            const int node = nbase + (l >> 4) * 4 + j;
            if (node < N_NODES) {
                float z = 0.0f;
                #pragma unroll
                for (int h = 0; h < 4; ++h)
                    z += (bf2f(avbh[(size_t)node * 512 + h * 128 + col]) + acc[h][nn][j])
                         * inv_sw[j][h];
                z = 0.25f * z + sq[(size_t)node * 384 + col];
                float si = z / (1.0f + __expf(-z));
                out[node * CHAN + col] = nf[node * CHAN + col] + si;
            }
        }
    }
}

// ---------------- launcher ---------------------------------------------------
extern "C" void kernel_launch(void* const* d_in, const int* in_sizes, int n_in,
                              void* d_out, int out_size, void* d_ws, size_t ws_size,
                              hipStream_t stream)
{
    const float* nf    = (const float*)d_in[0];
    const float* frac  = (const float*)d_in[1];
    const float* lat   = (const float*)d_in[2];
    const int*   eidx  = (const int*)  d_in[3];
    const int*   n2g   = (const int*)  d_in[4];
    const float* fdiff = (const float*)d_in[5];
    const float* gamma = (const float*)d_in[6];
    const float* beta  = (const float*)d_in[7];
    const float* Wq    = (const float*)d_in[8];
    const float* bq    = (const float*)d_in[9];
    const float* Wk    = (const float*)d_in[10];
    const float* bk    = (const float*)d_in[11];
    const float* Wv    = (const float*)d_in[12];
    const float* bv    = (const float*)d_in[13];
    const float* We    = (const float*)d_in[14];
    const float* Wsk   = (const float*)d_in[15];
    const float* bsk   = (const float*)d_in[16];
    float* out = (float*)d_out;

    // workspace layout
    float* sq        = (float*)d_ws;                               // N*384 (skip,qe)
    float* sumwbuf   = sq + (size_t)N_NODES * 384;                 // N*4
    float* bias_all  = sumwbuf + (size_t)N_NODES * 4;              // 1920
    float* sorted_fd = bias_all + NPAD;                            // E*3
    unsigned short* xfrag  = (unsigned short*)(sorted_fd + (size_t)N_EDGES * 3); // NR16*2560
    unsigned short* wfrag  = xfrag + (size_t)NR16 * FRAG_STRIDE;   // 120*2560
    unsigned short* webt   = wfrag + (size_t)(NPAD / 16) * FRAG_STRIDE; // 4*128*64
    unsigned short* aggbuf = webt + 4 * 128 * 64;                  // N*256
    unsigned short* qbuf   = aggbuf + (size_t)N_NODES * 256;       // N*512
    unsigned short* avbh   = qbuf + (size_t)N_NODES * 512;         // N*512 (bf16)
    unsigned char*  kvb    = (unsigned char*)(avbh + (size_t)N_NODES * 512); // N*4*256 bytes
    int* hist       = (int*)(kvb + (size_t)N_NODES * 4 * 256);     // N
    int* offsets    = hist + N_NODES;                              // N+1
    int* cursor     = offsets + N_NODES + 1;                       // N
    int* sorted_src = cursor + N_NODES;                            // E

    prep_weights_kernel<<<PREP_BLOCKS + TRANS_TILES + WQE_BLOCKS + WEBT_BLOCKS,
                          256, 0, stream>>>(
        nf, frac, lat, n2g, gamma, beta,
        Wq, bq, Wk, bk, Wv, bv, Wsk, bsk, We,
        xfrag, hist, wfrag, bias_all, webt);

    hist_kernel<<<(N_EDGES + 255) / 256, 256, 0, stream>>>(eidx, hist);
    scan_kernel<<<1, 1024, 0, stream>>>(hist, offsets, cursor);

    gemm_scatter_kernel<<<SCAT_BLOCKS + GEMM_BX * GEMM_BY, 256, 0, stream>>>(
        xfrag, wfrag, bias_all, eidx, fdiff, cursor, sorted_src, sorted_fd,
        sq, qbuf, kvb);

    gather_kernel<<<N_NODES, 256, 0, stream>>>(
        sq, qbuf, kvb, offsets, sorted_src, sorted_fd, avbh, aggbuf, sumwbuf);

    corrfin_kernel<<<(N_NODES + 63) / 64, 256, 0, stream>>>(
        webt, aggbuf, avbh, sumwbuf, sq, nf, out);
}